// Round 5
// baseline (424.450 us; speedup 1.0000x reference)
//
#include <hip/hip_runtime.h>
#include <hip/hip_bf16.h>

typedef unsigned short ushortT;
typedef __attribute__((ext_vector_type(8))) short bf16x8;
typedef __attribute__((ext_vector_type(4))) float f32x4;

// workspace float offsets
#define WS_XC   0          // 9216*256 fp32
#define WS_QB   2359296    // 9216*256 bf16 (1179648 floats)
#define WS_POS  3538944    // 16*36*3
#define WS_K    3540736    // 72*256
#define WS_V    3559168    // 72*256
#define WS_WC   3577600    // 256*256 fp32 (fallback path)
#define WS_WCB  3643136    // 256*256 bf16 = 32768 floats
#define WS_B512 3675904    // 512
#define WS_FLAG 3676416

__device__ __forceinline__ float bf2f(ushortT u) {
  union { unsigned int i; float f; } c; c.i = ((unsigned int)u) << 16; return c.f;
}
__device__ __forceinline__ ushortT f2bf(float f) {
  union { float f; unsigned int i; } c; c.f = f;
  unsigned int lsb = (c.i >> 16) & 1;
  return (ushortT)((c.i + 0x7fff + lsb) >> 16);
}
__device__ __forceinline__ float ldg_f(const void* p, int i, int bf) {
  return bf ? bf2f(((const ushortT*)p)[i]) : ((const float*)p)[i];
}

// ---------------- dtype detection ----------------
__global__ void k_detect(const void* x, int* flagout) {
  int lane = threadIdx.x;
  const ushortT* u = (const ushortT*)x;
  int wild = 0;
  for (int i = lane; i < 512; i += 64) {
    ushortT s = u[i];
    int e = (s >> 7) & 0xFF;
    if (e != 0 && (e < 90 || e > 160)) wild++;
  }
  for (int off = 32; off; off >>= 1) wild += __shfl_down(wild, off);
  if (lane == 0) flagout[0] = (wild > 40) ? 0 : 1;  // 1 => bf16 I/O
}

// ---------------- Wc = Wq*Win (fp32 + bf16), bias512 = [b_in | Wq*b_in + b_q] ----------------
__global__ __launch_bounds__(256) void k_wc(const void* w_in, const void* b_in, const void* w_q,
                                            const void* b_q, float* wc, ushortT* wcb,
                                            float* bias512, const int* flag) {
  int o = blockIdx.x, tid = threadIdx.x, bf = flag[0];
  __shared__ float wq_s[256];
  __shared__ float red[256];
  wq_s[tid] = ldg_f(w_q, o * 256 + tid, bf);
  __syncthreads();
  float s = 0.f;
#pragma unroll 8
  for (int j = 0; j < 256; j++) s += wq_s[j] * ldg_f(w_in, j * 256 + tid, bf);
  wc[o * 256 + tid] = s;
  wcb[o * 256 + tid] = f2bf(s);
  red[tid] = wq_s[tid] * ldg_f(b_in, tid, bf);
  __syncthreads();
  for (int m = 128; m; m >>= 1) {
    if (tid < m) red[tid] += red[tid + m];
    __syncthreads();
  }
  if (tid == 0) bias512[256 + o] = red[0] + ldg_f(b_q, o, bf);
  if (o == 0) bias512[tid] = ldg_f(b_in, tid, bf);
}

// ---------------- fused MFMA GEMM: [xc | q] = x * [Win^T | Wc^T] + bias512 ----------------
// M=9216, N=512, K=256. BM=BN=64, BK=32, 4 waves (2x2 of 32x32).
// grid: 1152 = 8 colT * 144 rowT
__global__ __launch_bounds__(256) void k_gemm_mfma(const void* x, const void* w_in, const float* wc,
                                                   const ushortT* wcb, const float* bias512,
                                                   float* xc, ushortT* qb, const int* flag) {
  const int bf = flag[0];
  __shared__ ushortT As[64 * 40];   // row stride 40 bf16 = 80B (2-way max conflict)
  __shared__ ushortT Bs[64 * 40];
  int tid = threadIdx.x;
  int bid = blockIdx.x;
  int colT = bid / 144, rowT = bid % 144;
  int col0 = colT * 64;
  int row0 = rowT * 64;
  int bt = row0 / 576;            // 576 % 64 == 0: tiles never cross bt
  int hw0 = row0 % 576;
  const int isW = (col0 < 256);

  if (bf) {
    const ushortT* xB = (const ushortT*)x;
    const ushortT* wB = (const ushortT*)w_in;
    // staging roles
    int ar = tid & 63, aoct = tid >> 6;          // A: row, k-octet
    int bn = tid >> 2, bko = tid & 3;            // B: n, k-octet
    const ushortT* bsrc = isW ? (wB + (col0 + bn) * 256)
                              : (wcb + (col0 - 256 + bn) * 256);
    // wave roles
    int w = tid >> 6, l = tid & 63;
    int wr = w >> 1, wcq = w & 1;
    int lr = l & 15, lk = l >> 4;
    f32x4 acc[2][2] = {};

    for (int kt = 0; kt < 8; kt++) {
      // ---- stage A: 8 strided bf16 loads (coalesced across lanes), pack, 1 ds_write_b128
      {
        int kbase = (bt * 256 + kt * 32 + aoct * 8) * 576 + hw0 + ar;
        unsigned int t0 = xB[kbase + 0 * 576], t1 = xB[kbase + 1 * 576];
        unsigned int t2 = xB[kbase + 2 * 576], t3 = xB[kbase + 3 * 576];
        unsigned int t4 = xB[kbase + 4 * 576], t5 = xB[kbase + 5 * 576];
        unsigned int t6 = xB[kbase + 6 * 576], t7 = xB[kbase + 7 * 576];
        int4 pk;
        pk.x = (int)(t0 | (t1 << 16)); pk.y = (int)(t2 | (t3 << 16));
        pk.z = (int)(t4 | (t5 << 16)); pk.w = (int)(t6 | (t7 << 16));
        *(int4*)&As[ar * 40 + aoct * 8] = pk;
      }
      // ---- stage B: one 16B load (k-contiguous), 1 ds_write_b128
      {
        int4 val = *(const int4*)(bsrc + kt * 32 + bko * 8);
        *(int4*)&Bs[bn * 40 + bko * 8] = val;
      }
      __syncthreads();
      bf16x8 af0 = *(const bf16x8*)&As[(wr * 32 + 0 * 16 + lr) * 40 + lk * 8];
      bf16x8 af1 = *(const bf16x8*)&As[(wr * 32 + 1 * 16 + lr) * 40 + lk * 8];
      bf16x8 bf0 = *(const bf16x8*)&Bs[(wcq * 32 + 0 * 16 + lr) * 40 + lk * 8];
      bf16x8 bf1 = *(const bf16x8*)&Bs[(wcq * 32 + 1 * 16 + lr) * 40 + lk * 8];
      acc[0][0] = __builtin_amdgcn_mfma_f32_16x16x32_bf16(af0, bf0, acc[0][0], 0, 0, 0);
      acc[0][1] = __builtin_amdgcn_mfma_f32_16x16x32_bf16(af0, bf1, acc[0][1], 0, 0, 0);
      acc[1][0] = __builtin_amdgcn_mfma_f32_16x16x32_bf16(af1, bf0, acc[1][0], 0, 0, 0);
      acc[1][1] = __builtin_amdgcn_mfma_f32_16x16x32_bf16(af1, bf1, acc[1][1], 0, 0, 0);
      __syncthreads();
    }
    // ---- epilogue: C/D col=lane&15, row=(lane>>4)*4+reg
#pragma unroll
    for (int m = 0; m < 2; m++) {
#pragma unroll
      for (int n = 0; n < 2; n++) {
#pragma unroll
        for (int i = 0; i < 4; i++) {
          int row = row0 + wr * 32 + m * 16 + lk * 4 + i;
          int col = col0 + wcq * 32 + n * 16 + lr;
          float v = acc[m][n][i] + bias512[col];
          if (isW) xc[row * 256 + col] = v;
          else     qb[row * 256 + (col - 256)] = f2bf(v);
        }
      }
    }
  } else {
    // correctness-only fp32 fallback (never taken when inputs are bf16)
    const float* xF = (const float*)x;
    const float* wF = (const float*)w_in;
    int r = row0 + (tid & 63);
    int cb = (tid >> 6) * 16;
#pragma unroll 1
    for (int c = 0; c < 16; c++) {
      int col = col0 + cb + c;
      const float* wrow = isW ? (wF + col * 256) : (wc + (col - 256) * 256);
      float s = 0.f;
      for (int k = 0; k < 256; k++)
        s += xF[(bt * 256 + k) * 576 + hw0 + (tid & 63)] * wrow[k];
      s += bias512[col];
      if (isW) xc[r * 256 + col] = s;
      else     qb[r * 256 + (col - 256)] = f2bf(s);
    }
  }
}

// ---------------- offsets: dw-conv + LN + GELU + proj + ref + clip ----------------
__global__ __launch_bounds__(64) void k_offsets(const ushortT* qb, const void* w_dw, const void* b_dw,
                                                const void* ln_g, const void* ln_b, const void* w_proj,
                                                float* pos, const int* flag) {
  int bid = blockIdx.x;           // g*36 + nn
  int g = bid / 36, nn = bid % 36;
  int b = g >> 3, nh = g & 7;
  int tk = nn / 9, hk = (nn / 3) % 3, wk = nn % 3;
  int lane = threadIdx.x;
  int ch = lane & 31, half = lane >> 5;
  int bf = flag[0];
  float sum = 0.f;
  for (int tap = half; tap < 243; tap += 2) {
    int dt = tap / 81, rem = tap % 81, dh = rem / 9, dw = rem % 9;
    int t = tk * 2 - 1 + dt, h = hk * 8 - 4 + dh, w = wk * 8 - 4 + dw;
    if (t < 0 || t >= 8 || h < 0 || h >= 24 || w < 0 || w >= 24) continue;
    float qv = bf2f(qb[((b * 8 + t) * 576 + h * 24 + w) * 256 + nh * 32 + ch]);
    float wv = ldg_f(w_dw, ((ch * 3 + dt) * 9 + dh) * 9 + dw, bf);
    sum += qv * wv;
  }
  sum += __shfl_xor(sum, 32);
  float v = sum + ldg_f(b_dw, ch, bf);
  float s1 = v;
  for (int m = 16; m; m >>= 1) s1 += __shfl_xor(s1, m);
  float mu = s1 * (1.f / 32.f);
  float d = v - mu;
  float s2 = d * d;
  for (int m = 16; m; m >>= 1) s2 += __shfl_xor(s2, m);
  float o = d * rsqrtf(s2 * (1.f / 32.f) + 1e-5f) * ldg_f(ln_g, ch, bf) + ldg_f(ln_b, ch, bf);
  o = 0.5f * o * (1.f + erff(o * 0.70710678118654752f));
  float res[3];
#pragma unroll
  for (int p = 0; p < 3; p++) {
    float t3 = o * ldg_f(w_proj, p * 32 + ch, bf);
    for (int m = 16; m; m >>= 1) t3 += __shfl_xor(t3, m);
    res[p] = t3;
  }
  if (lane == 0) {
    float ref0 = ((tk + 0.5f) / 3.f) * 2.f - 1.f;
    float ref1 = ((hk + 0.5f) / 2.f) * 2.f - 1.f;
    float ref2 = ((wk + 0.5f) / 2.f) * 2.f - 1.f;
    pos[bid * 3 + 0] = fminf(1.f, fmaxf(-1.f, res[0] + ref0));
    pos[bid * 3 + 1] = fminf(1.f, fmaxf(-1.f, res[1] + ref1));
    pos[bid * 3 + 2] = fminf(1.f, fmaxf(-1.f, res[2] + ref2));
  }
}

// ---------------- fused trilinear sample + k/v 1x1 conv (sel per block) ----------------
__global__ __launch_bounds__(256) void k_svkv(const float* xc_rm, const float* pos,
                                              const void* w_k, const void* b_k,
                                              const void* w_v, const void* b_v,
                                              float* k_rm, float* v_rm, const int* flag) {
  int bx = blockIdx.x;            // (b*36+nn)*2 + sel
  int sel = bx & 1, row = bx >> 1;
  int b = row / 36, nn = row % 36;
  int tid = threadIdx.x;
  int bf = flag[0];
  __shared__ float a[256];
  {
    int nh = tid >> 5;
    int g = b * 8 + nh;
    float p0 = pos[(g * 36 + nn) * 3 + 0];
    float p1 = pos[(g * 36 + nn) * 3 + 1];
    float p2 = pos[(g * 36 + nn) * 3 + 2];
    // faithful: gx=pos_t -> W axis, gy=pos_x -> H axis, gz=pos_y -> T axis
    float ix = (p0 + 1.f) * 0.5f * 23.f;
    float iy = (p2 + 1.f) * 0.5f * 23.f;
    float iz = (p1 + 1.f) * 0.5f * 7.f;
    float x0f = floorf(ix), y0f = floorf(iy), z0f = floorf(iz);
    float fx = ix - x0f, fy = iy - y0f, fz = iz - z0f;
    int x0 = min(max((int)x0f, 0), 23), x1 = min(x0 + 1, 23);
    int y0 = min(max((int)y0f, 0), 23), y1 = min(y0 + 1, 23);
    int z0 = min(max((int)z0f, 0), 7),  z1 = min(z0 + 1, 7);
#define AT(z, y, x) xc_rm[(((b * 8 + (z)) * 576 + (y) * 24 + (x)) * 256 + tid)]
    a[tid] =
      AT(z0, y0, x0) * (1.f - fz) * (1.f - fy) * (1.f - fx) + AT(z0, y0, x1) * (1.f - fz) * (1.f - fy) * fx +
      AT(z0, y1, x0) * (1.f - fz) * fy * (1.f - fx)         + AT(z0, y1, x1) * (1.f - fz) * fy * fx +
      AT(z1, y0, x0) * fz * (1.f - fy) * (1.f - fx)         + AT(z1, y0, x1) * fz * (1.f - fy) * fx +
      AT(z1, y1, x0) * fz * fy * (1.f - fx)                 + AT(z1, y1, x1) * fz * fy * fx;
#undef AT
  }
  __syncthreads();
  const void* w = sel ? w_v : w_k;
  const void* bb = sel ? b_v : b_k;
  float s = 0.f;
  if (bf) {
    const ushortT* wp = (const ushortT*)w + tid * 256;
#pragma unroll 4
    for (int c = 0; c < 256; c += 8) {
      ushort4 k0 = *(const ushort4*)(wp + c), k1 = *(const ushort4*)(wp + c + 4);
      s += a[c+0]*bf2f(k0.x) + a[c+1]*bf2f(k0.y) + a[c+2]*bf2f(k0.z) + a[c+3]*bf2f(k0.w)
         + a[c+4]*bf2f(k1.x) + a[c+5]*bf2f(k1.y) + a[c+6]*bf2f(k1.z) + a[c+7]*bf2f(k1.w);
    }
  } else {
    const float* wp = (const float*)w + tid * 256;
#pragma unroll 4
    for (int c = 0; c < 256; c += 4) {
      float4 k4 = *(const float4*)(wp + c);
      s += a[c]*k4.x + a[c+1]*k4.y + a[c+2]*k4.z + a[c+3]*k4.w;
    }
  }
  float* outp = sel ? v_rm : k_rm;
  outp[row * 256 + tid] = s + ldg_f(bb, tid, bf);
}

// ---------------- attention: QK + log-CPB bias + softmax + PV ----------------
__global__ __launch_bounds__(256) void k_attn(const ushortT* qb, const float* k_rm, const float* v_rm,
                                              const float* pos, const void* rpe_w1, const void* rpe_b1,
                                              const void* rpe_w2, void* outp, const int* flag) {
  __shared__ float ks[36][32];
  __shared__ float vs[36][32];
  __shared__ float poss[36][4];
  __shared__ float4 wab[32];
  __shared__ float w2s[32];
  int g = blockIdx.y, b = g >> 3, nh = g & 7;
  int tid = threadIdx.x;
  int bf = flag[0];
  for (int e = tid; e < 36 * 32; e += 256) {
    int nn = e >> 5, ch = e & 31;
    ks[nn][ch] = k_rm[(b * 36 + nn) * 256 + nh * 32 + ch];
    vs[nn][ch] = v_rm[(b * 36 + nn) * 256 + nh * 32 + ch];
  }
  if (tid < 32) {
    wab[tid] = make_float4(ldg_f(rpe_w1, tid * 3 + 0, bf), ldg_f(rpe_w1, tid * 3 + 1, bf),
                           ldg_f(rpe_w1, tid * 3 + 2, bf), ldg_f(rpe_b1, tid, bf));
    w2s[tid] = ldg_f(rpe_w2, tid, bf);
  }
  if (tid < 108) poss[tid / 3][tid % 3] = pos[g * 108 + tid];
  __syncthreads();

  int mm = blockIdx.x * 256 + tid;
  int t = mm / 576, hw = mm % 576, hh = hw / 24, wwi = hw % 24;
  float qreg[32];
  const ushort4* qp = (const ushort4*)&qb[(b * 4608 + mm) * 256 + nh * 32];
#pragma unroll
  for (int i = 0; i < 8; i++) {
    ushort4 u = qp[i];
    qreg[i * 4 + 0] = bf2f(u.x); qreg[i * 4 + 1] = bf2f(u.y);
    qreg[i * 4 + 2] = bf2f(u.z); qreg[i * 4 + 3] = bf2f(u.w);
  }
  float qg0 = t * (2.f / 7.f) - 1.f;
  float qg1 = hh * (2.f / 23.f) - 1.f;
  float qg2 = wwi * (2.f / 23.f) - 1.f;
  const float scale = 0.17677669529663687f;
  float p[36];
  float mx = -1e30f;
#pragma unroll
  for (int nn = 0; nn < 36; nn++) {
    float s = 0.f;
#pragma unroll
    for (int ch = 0; ch < 32; ch++) s += qreg[ch] * ks[nn][ch];
    float d0 = (qg0 - poss[nn][0]) * 4.f;
    float d1 = (qg1 - poss[nn][1]) * 4.f;
    float d2 = (qg2 - poss[nn][2]) * 4.f;
    d0 = copysignf(__log2f(fabsf(d0) + 1.f) * (1.f / 3.f), d0);
    d1 = copysignf(__log2f(fabsf(d1) + 1.f) * (1.f / 3.f), d1);
    d2 = copysignf(__log2f(fabsf(d2) + 1.f) * (1.f / 3.f), d2);
    float bias = 0.f;
#pragma unroll
    for (int h = 0; h < 32; h++) {
      float4 w = wab[h];
      float hb = fmaf(d0, w.x, fmaf(d1, w.y, fmaf(d2, w.z, w.w)));
      bias = fmaf(fmaxf(hb, 0.f), w2s[h], bias);
    }
    float L = fmaf(s, scale, bias);
    p[nn] = L;
    mx = fmaxf(mx, L);
  }
  float se = 0.f;
#pragma unroll
  for (int nn = 0; nn < 36; nn++) {
    float e = __expf(p[nn] - mx);
    p[nn] = e;
    se += e;
  }
  float inv = 1.f / se;
  float acc[32] = {};
#pragma unroll
  for (int nn = 0; nn < 36; nn++) {
    float pr = p[nn] * inv;
#pragma unroll
    for (int ch = 0; ch < 32; ch++) acc[ch] += pr * vs[nn][ch];
  }
  int obase = ((b * 8 + t) * 256 + nh * 32) * 576 + hw;
  if (bf) {
    __hip_bfloat16* o = (__hip_bfloat16*)outp;
#pragma unroll
    for (int ch = 0; ch < 32; ch++) o[obase + ch * 576] = __float2bfloat16(acc[ch]);
  } else {
    float* o = (float*)outp;
#pragma unroll
    for (int ch = 0; ch < 32; ch++) o[obase + ch * 576] = acc[ch];
  }
}

extern "C" void kernel_launch(void* const* d_in, const int* in_sizes, int n_in,
                              void* d_out, int out_size, void* d_ws, size_t ws_size,
                              hipStream_t stream) {
  const void* x        = d_in[0];
  const void* w_in     = d_in[1];
  const void* b_in     = d_in[2];
  const void* w_q      = d_in[3];
  const void* b_q      = d_in[4];
  const void* w_off_dw = d_in[5];
  const void* b_off_dw = d_in[6];
  const void* ln_g     = d_in[7];
  const void* ln_b     = d_in[8];
  const void* w_off_pj = d_in[9];
  const void* w_k      = d_in[10];
  const void* b_k      = d_in[11];
  const void* w_v      = d_in[12];
  const void* b_v      = d_in[13];
  const void* rpe_w1   = d_in[14];
  const void* rpe_b1   = d_in[15];
  const void* rpe_w2   = d_in[16];

  float* ws    = (float*)d_ws;
  float* xc    = ws + WS_XC;
  ushortT* qb  = (ushortT*)(ws + WS_QB);
  float* pos   = ws + WS_POS;
  float* krm   = ws + WS_K;
  float* vrm   = ws + WS_V;
  float* wcf   = ws + WS_WC;
  ushortT* wcb = (ushortT*)(ws + WS_WCB);
  float* b512  = ws + WS_B512;
  int* flag    = (int*)(ws + WS_FLAG);

  k_detect<<<1, 64, 0, stream>>>(x, flag);
  k_wc<<<256, 256, 0, stream>>>(w_in, b_in, w_q, b_q, wcf, wcb, b512, flag);
  k_gemm_mfma<<<1152, 256, 0, stream>>>(x, w_in, wcf, wcb, b512, xc, qb, flag);
  k_offsets<<<576, 64, 0, stream>>>(qb, w_off_dw, b_off_dw, ln_g, ln_b, w_off_pj, pos, flag);
  k_svkv<<<144, 256, 0, stream>>>(xc, pos, w_k, b_k, w_v, b_v, krm, vrm, flag);
  k_attn<<<dim3(18, 16), 256, 0, stream>>>(qb, krm, vrm, pos, rpe_w1, rpe_b1, rpe_w2, d_out, flag);
}

// Round 6
// 142.453 us; speedup vs baseline: 2.9796x; 2.9796x over previous
//
#include <hip/hip_runtime.h>
#include <hip/hip_bf16.h>

typedef unsigned short ushortT;
typedef __attribute__((ext_vector_type(8))) short bf16x8;
typedef __attribute__((ext_vector_type(4))) float f32x4;

// workspace float offsets
#define WS_XC   0          // 9216*256 fp32
#define WS_QB   2359296    // 9216*256 bf16 (1179648 floats)
#define WS_POS  3538944    // 16*36*3
#define WS_K    3540736    // 72*256
#define WS_V    3559168    // 72*256
#define WS_WC   3577600    // 256*256 fp32
#define WS_B512 3675904    // 512
#define WS_FLAG 3676416

__device__ __forceinline__ float bf2f(ushortT u) {
  union { unsigned int i; float f; } c; c.i = ((unsigned int)u) << 16; return c.f;
}
__device__ __forceinline__ ushortT f2bf(float f) {
  union { float f; unsigned int i; } c; c.f = f;
  unsigned int lsb = (c.i >> 16) & 1;
  return (ushortT)((c.i + 0x7fff + lsb) >> 16);
}
__device__ __forceinline__ float ldg_f(const void* p, int i, int bf) {
  return bf ? bf2f(((const ushortT*)p)[i]) : ((const float*)p)[i];
}

// ---------------- dtype detection (empirically: fp32 on this harness) ----------------
__global__ void k_detect(const void* x, int* flagout) {
  int lane = threadIdx.x;
  const ushortT* u = (const ushortT*)x;
  int wild = 0;
  for (int i = lane; i < 512; i += 64) {
    ushortT s = u[i];
    int e = (s >> 7) & 0xFF;
    if (e != 0 && (e < 90 || e > 160)) wild++;
  }
  for (int off = 32; off; off >>= 1) wild += __shfl_down(wild, off);
  if (lane == 0) flagout[0] = (wild > 40) ? 0 : 1;  // 1 => bf16 I/O
}

// ---------------- Wc = Wq*Win (fp32), bias512 = [b_in | Wq*b_in + b_q] ----------------
__global__ __launch_bounds__(256) void k_wc(const void* w_in, const void* b_in, const void* w_q,
                                            const void* b_q, float* wc, float* bias512, const int* flag) {
  int o = blockIdx.x, tid = threadIdx.x, bf = flag[0];
  __shared__ float wq_s[256];
  __shared__ float red[256];
  wq_s[tid] = ldg_f(w_q, o * 256 + tid, bf);
  __syncthreads();
  float s = 0.f;
#pragma unroll 8
  for (int j = 0; j < 256; j++) s += wq_s[j] * ldg_f(w_in, j * 256 + tid, bf);
  wc[o * 256 + tid] = s;
  red[tid] = wq_s[tid] * ldg_f(b_in, tid, bf);
  __syncthreads();
  for (int m = 128; m; m >>= 1) {
    if (tid < m) red[tid] += red[tid + m];
    __syncthreads();
  }
  if (tid == 0) bias512[256 + o] = red[0] + ldg_f(b_q, o, bf);
  if (o == 0) bias512[tid] = ldg_f(b_in, tid, bf);
}

// ---------------- fused split-precision MFMA GEMM: [xc | q] = x*[Win^T | Wc^T]+bias ----------------
// fp32 inputs -> (hi,lo) bf16 split; acc += Ah*Bh + Ah*Bl + Al*Bh  (AlBl ~2^-18, dropped)
// M=9216, N=512, K=256. BM=BN=64, BK=32, 4 waves (2x2 of 32x32). grid 1152 = 8 colT * 144 rowT.
__global__ __launch_bounds__(256) void k_gemm_mfma(const void* x, const void* w_in, const float* wc,
                                                   const float* bias512, float* xc, ushortT* qb,
                                                   const int* flag) {
  const int bf = flag[0];
  __shared__ ushortT Ah[64 * 40], Al[64 * 40];
  __shared__ ushortT Bh[64 * 40], Bl[64 * 40];
  int tid = threadIdx.x;
  int bid = blockIdx.x;
  int colT = bid / 144, rowT = bid % 144;
  int col0 = colT * 64;
  int row0 = rowT * 64;
  int bt = row0 / 576;            // 576 % 64 == 0: tiles never cross bt
  int hw0 = row0 % 576;
  const int isW = (col0 < 256);
  const ushortT* xB = (const ushortT*)x;
  const float*   xF = (const float*)x;
  const ushortT* wB = (const ushortT*)w_in;
  const float*   wF = (const float*)w_in;
  // staging roles
  int ar = tid & 63, aoct = tid >> 6;          // A: row, k-octet (0..3)
  int bn = tid >> 2, bko = tid & 3;            // B: n, k-octet (0..3)
  // wave roles
  int w = tid >> 6, l = tid & 63;
  int wr = w >> 1, wcq = w & 1;
  int lr = l & 15, lk = l >> 4;
  f32x4 acc[2][2] = {};

  for (int kt = 0; kt < 8; kt++) {
    // ---- stage A: 8 coalesced fp32 loads (k-strided), split hi/lo, 2x ds_write_b128
    {
      int kbase = (bt * 256 + kt * 32 + aoct * 8) * 576 + hw0 + ar;
      ushortT hi[8], lo[8];
#pragma unroll
      for (int j = 0; j < 8; j++) {
        float v = bf ? bf2f(xB[kbase + j * 576]) : xF[kbase + j * 576];
        ushortT h = f2bf(v);
        hi[j] = h;
        lo[j] = f2bf(v - bf2f(h));
      }
      int4 ph, pl;
      ph.x = (int)((unsigned)hi[0] | ((unsigned)hi[1] << 16));
      ph.y = (int)((unsigned)hi[2] | ((unsigned)hi[3] << 16));
      ph.z = (int)((unsigned)hi[4] | ((unsigned)hi[5] << 16));
      ph.w = (int)((unsigned)hi[6] | ((unsigned)hi[7] << 16));
      pl.x = (int)((unsigned)lo[0] | ((unsigned)lo[1] << 16));
      pl.y = (int)((unsigned)lo[2] | ((unsigned)lo[3] << 16));
      pl.z = (int)((unsigned)lo[4] | ((unsigned)lo[5] << 16));
      pl.w = (int)((unsigned)lo[6] | ((unsigned)lo[7] << 16));
      *(int4*)&Ah[ar * 40 + aoct * 8] = ph;
      *(int4*)&Al[ar * 40 + aoct * 8] = pl;
    }
    // ---- stage B: 8 fp32 (k-contiguous), split hi/lo, 2x ds_write_b128
    {
      float vb[8];
      if (isW) {
        if (bf) {
          const ushortT* pp = wB + (col0 + bn) * 256 + kt * 32 + bko * 8;
#pragma unroll
          for (int j = 0; j < 8; j++) vb[j] = bf2f(pp[j]);
        } else {
          const float* pp = wF + (col0 + bn) * 256 + kt * 32 + bko * 8;
          float4 f0 = *(const float4*)pp;
          float4 f1 = *(const float4*)(pp + 4);
          vb[0] = f0.x; vb[1] = f0.y; vb[2] = f0.z; vb[3] = f0.w;
          vb[4] = f1.x; vb[5] = f1.y; vb[6] = f1.z; vb[7] = f1.w;
        }
      } else {
        const float* pp = wc + (col0 - 256 + bn) * 256 + kt * 32 + bko * 8;
        float4 f0 = *(const float4*)pp;
        float4 f1 = *(const float4*)(pp + 4);
        vb[0] = f0.x; vb[1] = f0.y; vb[2] = f0.z; vb[3] = f0.w;
        vb[4] = f1.x; vb[5] = f1.y; vb[6] = f1.z; vb[7] = f1.w;
      }
      ushortT hi[8], lo[8];
#pragma unroll
      for (int j = 0; j < 8; j++) {
        ushortT h = f2bf(vb[j]);
        hi[j] = h;
        lo[j] = f2bf(vb[j] - bf2f(h));
      }
      int4 ph, pl;
      ph.x = (int)((unsigned)hi[0] | ((unsigned)hi[1] << 16));
      ph.y = (int)((unsigned)hi[2] | ((unsigned)hi[3] << 16));
      ph.z = (int)((unsigned)hi[4] | ((unsigned)hi[5] << 16));
      ph.w = (int)((unsigned)hi[6] | ((unsigned)hi[7] << 16));
      pl.x = (int)((unsigned)lo[0] | ((unsigned)lo[1] << 16));
      pl.y = (int)((unsigned)lo[2] | ((unsigned)lo[3] << 16));
      pl.z = (int)((unsigned)lo[4] | ((unsigned)lo[5] << 16));
      pl.w = (int)((unsigned)lo[6] | ((unsigned)lo[7] << 16));
      *(int4*)&Bh[bn * 40 + bko * 8] = ph;
      *(int4*)&Bl[bn * 40 + bko * 8] = pl;
    }
    __syncthreads();
    // ---- fragments: A row = l&15, k = (l>>4)*8+j ; B col = l&15, same k
    bf16x8 a0h = *(const bf16x8*)&Ah[(wr * 32 + 0 * 16 + lr) * 40 + lk * 8];
    bf16x8 a1h = *(const bf16x8*)&Ah[(wr * 32 + 1 * 16 + lr) * 40 + lk * 8];
    bf16x8 a0l = *(const bf16x8*)&Al[(wr * 32 + 0 * 16 + lr) * 40 + lk * 8];
    bf16x8 a1l = *(const bf16x8*)&Al[(wr * 32 + 1 * 16 + lr) * 40 + lk * 8];
    bf16x8 b0h = *(const bf16x8*)&Bh[(wcq * 32 + 0 * 16 + lr) * 40 + lk * 8];
    bf16x8 b1h = *(const bf16x8*)&Bh[(wcq * 32 + 1 * 16 + lr) * 40 + lk * 8];
    bf16x8 b0l = *(const bf16x8*)&Bl[(wcq * 32 + 0 * 16 + lr) * 40 + lk * 8];
    bf16x8 b1l = *(const bf16x8*)&Bl[(wcq * 32 + 1 * 16 + lr) * 40 + lk * 8];
    acc[0][0] = __builtin_amdgcn_mfma_f32_16x16x32_bf16(a0h, b0h, acc[0][0], 0, 0, 0);
    acc[0][0] = __builtin_amdgcn_mfma_f32_16x16x32_bf16(a0h, b0l, acc[0][0], 0, 0, 0);
    acc[0][0] = __builtin_amdgcn_mfma_f32_16x16x32_bf16(a0l, b0h, acc[0][0], 0, 0, 0);
    acc[0][1] = __builtin_amdgcn_mfma_f32_16x16x32_bf16(a0h, b1h, acc[0][1], 0, 0, 0);
    acc[0][1] = __builtin_amdgcn_mfma_f32_16x16x32_bf16(a0h, b1l, acc[0][1], 0, 0, 0);
    acc[0][1] = __builtin_amdgcn_mfma_f32_16x16x32_bf16(a0l, b1h, acc[0][1], 0, 0, 0);
    acc[1][0] = __builtin_amdgcn_mfma_f32_16x16x32_bf16(a1h, b0h, acc[1][0], 0, 0, 0);
    acc[1][0] = __builtin_amdgcn_mfma_f32_16x16x32_bf16(a1h, b0l, acc[1][0], 0, 0, 0);
    acc[1][0] = __builtin_amdgcn_mfma_f32_16x16x32_bf16(a1l, b0h, acc[1][0], 0, 0, 0);
    acc[1][1] = __builtin_amdgcn_mfma_f32_16x16x32_bf16(a1h, b1h, acc[1][1], 0, 0, 0);
    acc[1][1] = __builtin_amdgcn_mfma_f32_16x16x32_bf16(a1h, b1l, acc[1][1], 0, 0, 0);
    acc[1][1] = __builtin_amdgcn_mfma_f32_16x16x32_bf16(a1l, b1h, acc[1][1], 0, 0, 0);
    __syncthreads();
  }
  // ---- epilogue: C/D col=lane&15, row=(lane>>4)*4+reg (verified mapping)
#pragma unroll
  for (int m = 0; m < 2; m++) {
#pragma unroll
    for (int n = 0; n < 2; n++) {
#pragma unroll
      for (int i = 0; i < 4; i++) {
        int row = row0 + wr * 32 + m * 16 + lk * 4 + i;
        int col = col0 + wcq * 32 + n * 16 + lr;
        float v = acc[m][n][i] + bias512[col];
        if (isW) xc[row * 256 + col] = v;
        else     qb[row * 256 + (col - 256)] = f2bf(v);
      }
    }
  }
}

// ---------------- offsets: dw-conv + LN + GELU + proj + ref + clip ----------------
__global__ __launch_bounds__(64) void k_offsets(const ushortT* qb, const void* w_dw, const void* b_dw,
                                                const void* ln_g, const void* ln_b, const void* w_proj,
                                                float* pos, const int* flag) {
  int bid = blockIdx.x;           // g*36 + nn
  int g = bid / 36, nn = bid % 36;
  int b = g >> 3, nh = g & 7;
  int tk = nn / 9, hk = (nn / 3) % 3, wk = nn % 3;
  int lane = threadIdx.x;
  int ch = lane & 31, half = lane >> 5;
  int bf = flag[0];
  float sum = 0.f;
  for (int tap = half; tap < 243; tap += 2) {
    int dt = tap / 81, rem = tap % 81, dh = rem / 9, dw = rem % 9;
    int t = tk * 2 - 1 + dt, h = hk * 8 - 4 + dh, w = wk * 8 - 4 + dw;
    if (t < 0 || t >= 8 || h < 0 || h >= 24 || w < 0 || w >= 24) continue;
    float qv = bf2f(qb[((b * 8 + t) * 576 + h * 24 + w) * 256 + nh * 32 + ch]);
    float wv = ldg_f(w_dw, ((ch * 3 + dt) * 9 + dh) * 9 + dw, bf);
    sum += qv * wv;
  }
  sum += __shfl_xor(sum, 32);
  float v = sum + ldg_f(b_dw, ch, bf);
  float s1 = v;
  for (int m = 16; m; m >>= 1) s1 += __shfl_xor(s1, m);
  float mu = s1 * (1.f / 32.f);
  float d = v - mu;
  float s2 = d * d;
  for (int m = 16; m; m >>= 1) s2 += __shfl_xor(s2, m);
  float o = d * rsqrtf(s2 * (1.f / 32.f) + 1e-5f) * ldg_f(ln_g, ch, bf) + ldg_f(ln_b, ch, bf);
  o = 0.5f * o * (1.f + erff(o * 0.70710678118654752f));
  float res[3];
#pragma unroll
  for (int p = 0; p < 3; p++) {
    float t3 = o * ldg_f(w_proj, p * 32 + ch, bf);
    for (int m = 16; m; m >>= 1) t3 += __shfl_xor(t3, m);
    res[p] = t3;
  }
  if (lane == 0) {
    float ref0 = ((tk + 0.5f) / 3.f) * 2.f - 1.f;
    float ref1 = ((hk + 0.5f) / 2.f) * 2.f - 1.f;
    float ref2 = ((wk + 0.5f) / 2.f) * 2.f - 1.f;
    pos[bid * 3 + 0] = fminf(1.f, fmaxf(-1.f, res[0] + ref0));
    pos[bid * 3 + 1] = fminf(1.f, fmaxf(-1.f, res[1] + ref1));
    pos[bid * 3 + 2] = fminf(1.f, fmaxf(-1.f, res[2] + ref2));
  }
}

// ---------------- fused trilinear sample + k/v 1x1 conv (sel per block) ----------------
__global__ __launch_bounds__(256) void k_svkv(const float* xc_rm, const float* pos,
                                              const void* w_k, const void* b_k,
                                              const void* w_v, const void* b_v,
                                              float* k_rm, float* v_rm, const int* flag) {
  int bx = blockIdx.x;            // (b*36+nn)*2 + sel
  int sel = bx & 1, row = bx >> 1;
  int b = row / 36, nn = row % 36;
  int tid = threadIdx.x;
  int bf = flag[0];
  __shared__ float a[256];
  {
    int nh = tid >> 5;
    int g = b * 8 + nh;
    float p0 = pos[(g * 36 + nn) * 3 + 0];
    float p1 = pos[(g * 36 + nn) * 3 + 1];
    float p2 = pos[(g * 36 + nn) * 3 + 2];
    // faithful: gx=pos_t -> W axis, gy=pos_x -> H axis, gz=pos_y -> T axis
    float ix = (p0 + 1.f) * 0.5f * 23.f;
    float iy = (p2 + 1.f) * 0.5f * 23.f;
    float iz = (p1 + 1.f) * 0.5f * 7.f;
    float x0f = floorf(ix), y0f = floorf(iy), z0f = floorf(iz);
    float fx = ix - x0f, fy = iy - y0f, fz = iz - z0f;
    int x0 = min(max((int)x0f, 0), 23), x1 = min(x0 + 1, 23);
    int y0 = min(max((int)y0f, 0), 23), y1 = min(y0 + 1, 23);
    int z0 = min(max((int)z0f, 0), 7),  z1 = min(z0 + 1, 7);
#define AT(z, y, x) xc_rm[(((b * 8 + (z)) * 576 + (y) * 24 + (x)) * 256 + tid)]
    a[tid] =
      AT(z0, y0, x0) * (1.f - fz) * (1.f - fy) * (1.f - fx) + AT(z0, y0, x1) * (1.f - fz) * (1.f - fy) * fx +
      AT(z0, y1, x0) * (1.f - fz) * fy * (1.f - fx)         + AT(z0, y1, x1) * (1.f - fz) * fy * fx +
      AT(z1, y0, x0) * fz * (1.f - fy) * (1.f - fx)         + AT(z1, y0, x1) * fz * (1.f - fy) * fx +
      AT(z1, y1, x0) * fz * fy * (1.f - fx)                 + AT(z1, y1, x1) * fz * fy * fx;
#undef AT
  }
  __syncthreads();
  const void* w = sel ? w_v : w_k;
  const void* bb = sel ? b_v : b_k;
  float s = 0.f;
  if (bf) {
    const ushortT* wp = (const ushortT*)w + tid * 256;
#pragma unroll 4
    for (int c = 0; c < 256; c += 8) {
      ushort4 k0 = *(const ushort4*)(wp + c), k1 = *(const ushort4*)(wp + c + 4);
      s += a[c+0]*bf2f(k0.x) + a[c+1]*bf2f(k0.y) + a[c+2]*bf2f(k0.z) + a[c+3]*bf2f(k0.w)
         + a[c+4]*bf2f(k1.x) + a[c+5]*bf2f(k1.y) + a[c+6]*bf2f(k1.z) + a[c+7]*bf2f(k1.w);
    }
  } else {
    const float* wp = (const float*)w + tid * 256;
#pragma unroll 4
    for (int c = 0; c < 256; c += 4) {
      float4 k4 = *(const float4*)(wp + c);
      s += a[c]*k4.x + a[c+1]*k4.y + a[c+2]*k4.z + a[c+3]*k4.w;
    }
  }
  float* outp = sel ? v_rm : k_rm;
  outp[row * 256 + tid] = s + ldg_f(bb, tid, bf);
}

// ---------------- attention: QK + log-CPB bias + softmax + PV ----------------
__global__ __launch_bounds__(256) void k_attn(const ushortT* qb, const float* k_rm, const float* v_rm,
                                              const float* pos, const void* rpe_w1, const void* rpe_b1,
                                              const void* rpe_w2, void* outp, const int* flag) {
  __shared__ float ks[36][32];
  __shared__ float vs[36][32];
  __shared__ float poss[36][4];
  __shared__ float4 wab[32];
  __shared__ float w2s[32];
  int g = blockIdx.y, b = g >> 3, nh = g & 7;
  int tid = threadIdx.x;
  int bf = flag[0];
  for (int e = tid; e < 36 * 32; e += 256) {
    int nn = e >> 5, ch = e & 31;
    ks[nn][ch] = k_rm[(b * 36 + nn) * 256 + nh * 32 + ch];
    vs[nn][ch] = v_rm[(b * 36 + nn) * 256 + nh * 32 + ch];
  }
  if (tid < 32) {
    wab[tid] = make_float4(ldg_f(rpe_w1, tid * 3 + 0, bf), ldg_f(rpe_w1, tid * 3 + 1, bf),
                           ldg_f(rpe_w1, tid * 3 + 2, bf), ldg_f(rpe_b1, tid, bf));
    w2s[tid] = ldg_f(rpe_w2, tid, bf);
  }
  if (tid < 108) poss[tid / 3][tid % 3] = pos[g * 108 + tid];
  __syncthreads();

  int mm = blockIdx.x * 256 + tid;
  int t = mm / 576, hw = mm % 576, hh = hw / 24, wwi = hw % 24;
  float qreg[32];
  const ushort4* qp = (const ushort4*)&qb[(b * 4608 + mm) * 256 + nh * 32];
#pragma unroll
  for (int i = 0; i < 8; i++) {
    ushort4 u = qp[i];
    qreg[i * 4 + 0] = bf2f(u.x); qreg[i * 4 + 1] = bf2f(u.y);
    qreg[i * 4 + 2] = bf2f(u.z); qreg[i * 4 + 3] = bf2f(u.w);
  }
  float qg0 = t * (2.f / 7.f) - 1.f;
  float qg1 = hh * (2.f / 23.f) - 1.f;
  float qg2 = wwi * (2.f / 23.f) - 1.f;
  const float scale = 0.17677669529663687f;
  float p[36];
  float mx = -1e30f;
#pragma unroll
  for (int nn = 0; nn < 36; nn++) {
    float s = 0.f;
#pragma unroll
    for (int ch = 0; ch < 32; ch++) s += qreg[ch] * ks[nn][ch];
    float d0 = (qg0 - poss[nn][0]) * 4.f;
    float d1 = (qg1 - poss[nn][1]) * 4.f;
    float d2 = (qg2 - poss[nn][2]) * 4.f;
    d0 = copysignf(__log2f(fabsf(d0) + 1.f) * (1.f / 3.f), d0);
    d1 = copysignf(__log2f(fabsf(d1) + 1.f) * (1.f / 3.f), d1);
    d2 = copysignf(__log2f(fabsf(d2) + 1.f) * (1.f / 3.f), d2);
    float bias = 0.f;
#pragma unroll
    for (int h = 0; h < 32; h++) {
      float4 w = wab[h];
      float hb = fmaf(d0, w.x, fmaf(d1, w.y, fmaf(d2, w.z, w.w)));
      bias = fmaf(fmaxf(hb, 0.f), w2s[h], bias);
    }
    float L = fmaf(s, scale, bias);
    p[nn] = L;
    mx = fmaxf(mx, L);
  }
  float se = 0.f;
#pragma unroll
  for (int nn = 0; nn < 36; nn++) {
    float e = __expf(p[nn] - mx);
    p[nn] = e;
    se += e;
  }
  float inv = 1.f / se;
  float acc[32] = {};
#pragma unroll
  for (int nn = 0; nn < 36; nn++) {
    float pr = p[nn] * inv;
#pragma unroll
    for (int ch = 0; ch < 32; ch++) acc[ch] += pr * vs[nn][ch];
  }
  int obase = ((b * 8 + t) * 256 + nh * 32) * 576 + hw;
  if (bf) {
    __hip_bfloat16* o = (__hip_bfloat16*)outp;
#pragma unroll
    for (int ch = 0; ch < 32; ch++) o[obase + ch * 576] = __float2bfloat16(acc[ch]);
  } else {
    float* o = (float*)outp;
#pragma unroll
    for (int ch = 0; ch < 32; ch++) o[obase + ch * 576] = acc[ch];
  }
}

extern "C" void kernel_launch(void* const* d_in, const int* in_sizes, int n_in,
                              void* d_out, int out_size, void* d_ws, size_t ws_size,
                              hipStream_t stream) {
  const void* x        = d_in[0];
  const void* w_in     = d_in[1];
  const void* b_in     = d_in[2];
  const void* w_q      = d_in[3];
  const void* b_q      = d_in[4];
  const void* w_off_dw = d_in[5];
  const void* b_off_dw = d_in[6];
  const void* ln_g     = d_in[7];
  const void* ln_b     = d_in[8];
  const void* w_off_pj = d_in[9];
  const void* w_k      = d_in[10];
  const void* b_k      = d_in[11];
  const void* w_v      = d_in[12];
  const void* b_v      = d_in[13];
  const void* rpe_w1   = d_in[14];
  const void* rpe_b1   = d_in[15];
  const void* rpe_w2   = d_in[16];

  float* ws    = (float*)d_ws;
  float* xc    = ws + WS_XC;
  ushortT* qb  = (ushortT*)(ws + WS_QB);
  float* pos   = ws + WS_POS;
  float* krm   = ws + WS_K;
  float* vrm   = ws + WS_V;
  float* wcf   = ws + WS_WC;
  float* b512  = ws + WS_B512;
  int* flag    = (int*)(ws + WS_FLAG);

  k_detect<<<1, 64, 0, stream>>>(x, flag);
  k_wc<<<256, 256, 0, stream>>>(w_in, b_in, w_q, b_q, wcf, b512, flag);
  k_gemm_mfma<<<1152, 256, 0, stream>>>(x, w_in, wcf, b512, xc, qb, flag);
  k_offsets<<<576, 64, 0, stream>>>(qb, w_off_dw, b_off_dw, ln_g, ln_b, w_off_pj, pos, flag);
  k_svkv<<<144, 256, 0, stream>>>(xc, pos, w_k, b_k, w_v, b_v, krm, vrm, flag);
  k_attn<<<dim3(18, 16), 256, 0, stream>>>(qb, krm, vrm, pos, rpe_w1, rpe_b1, rpe_w2, d_out, flag);
}

// Round 7
// 118.517 us; speedup vs baseline: 3.5813x; 1.2020x over previous
//
#include <hip/hip_runtime.h>
#include <hip/hip_bf16.h>

typedef unsigned short ushortT;
typedef __attribute__((ext_vector_type(8))) short bf16x8;
typedef __attribute__((ext_vector_type(4))) float f32x4;

// workspace float offsets
#define WS_XC   0          // 9216*256 fp32
#define WS_QB   2359296    // 9216*256 bf16 (1179648 floats)
#define WS_POS  3538944    // 16*36*3
#define WS_K    3540736    // 72*256
#define WS_V    3559168    // 72*256
#define WS_WC   3577600    // 256*256 fp32
#define WS_B512 3675904    // 512
#define WS_FLAG 3676416

__device__ __forceinline__ float bf2f(ushortT u) {
  union { unsigned int i; float f; } c; c.i = ((unsigned int)u) << 16; return c.f;
}
__device__ __forceinline__ ushortT f2bf(float f) {
  union { float f; unsigned int i; } c; c.f = f;
  unsigned int lsb = (c.i >> 16) & 1;
  return (ushortT)((c.i + 0x7fff + lsb) >> 16);
}
__device__ __forceinline__ float ldg_f(const void* p, int i, int bf) {
  return bf ? bf2f(((const ushortT*)p)[i]) : ((const float*)p)[i];
}

// ---------------- dtype detection (empirically: fp32 on this harness) ----------------
__global__ void k_detect(const void* x, int* flagout) {
  int lane = threadIdx.x;
  const ushortT* u = (const ushortT*)x;
  int wild = 0;
  for (int i = lane; i < 512; i += 64) {
    ushortT s = u[i];
    int e = (s >> 7) & 0xFF;
    if (e != 0 && (e < 90 || e > 160)) wild++;
  }
  for (int off = 32; off; off >>= 1) wild += __shfl_down(wild, off);
  if (lane == 0) flagout[0] = (wild > 40) ? 0 : 1;  // 1 => bf16 I/O
}

// ---------------- Wc = Wq*Win (fp32), bias512 = [b_in | Wq*b_in + b_q] ----------------
__global__ __launch_bounds__(256) void k_wc(const void* w_in, const void* b_in, const void* w_q,
                                            const void* b_q, float* wc, float* bias512, const int* flag) {
  int o = blockIdx.x, tid = threadIdx.x, bf = flag[0];
  __shared__ float wq_s[256];
  __shared__ float red[256];
  wq_s[tid] = ldg_f(w_q, o * 256 + tid, bf);
  __syncthreads();
  float s = 0.f;
#pragma unroll 8
  for (int j = 0; j < 256; j++) s += wq_s[j] * ldg_f(w_in, j * 256 + tid, bf);
  wc[o * 256 + tid] = s;
  red[tid] = wq_s[tid] * ldg_f(b_in, tid, bf);
  __syncthreads();
  for (int m = 128; m; m >>= 1) {
    if (tid < m) red[tid] += red[tid + m];
    __syncthreads();
  }
  if (tid == 0) bias512[256 + o] = red[0] + ldg_f(b_q, o, bf);
  if (o == 0) bias512[tid] = ldg_f(b_in, tid, bf);
}

// ---------------- fused split-precision MFMA GEMM: [xc | q] = x*[Win^T | Wc^T]+bias ----------------
// fp32 inputs -> (hi,lo) bf16 split; acc += Ah*Bh + Ah*Bl + Al*Bh  (AlBl ~2^-18, dropped)
// M=9216, N=512, K=256. BM=BN=64, BK=32, 4 waves (2x2 of 32x32). grid 1152 = 8 colT * 144 rowT.
__global__ __launch_bounds__(256) void k_gemm_mfma(const void* x, const void* w_in, const float* wc,
                                                   const float* bias512, float* xc, ushortT* qb,
                                                   const int* flag) {
  const int bf = flag[0];
  __shared__ ushortT Ah[64 * 40], Al[64 * 40];
  __shared__ ushortT Bh[64 * 40], Bl[64 * 40];
  int tid = threadIdx.x;
  int bid = blockIdx.x;
  int colT = bid / 144, rowT = bid % 144;
  int col0 = colT * 64;
  int row0 = rowT * 64;
  int bt = row0 / 576;            // 576 % 64 == 0: tiles never cross bt
  int hw0 = row0 % 576;
  const int isW = (col0 < 256);
  const ushortT* xB = (const ushortT*)x;
  const float*   xF = (const float*)x;
  const ushortT* wB = (const ushortT*)w_in;
  const float*   wF = (const float*)w_in;
  // staging roles
  int ar = tid & 63, aoct = tid >> 6;          // A: row, k-octet (0..3)
  int bn = tid >> 2, bko = tid & 3;            // B: n, k-octet (0..3)
  // wave roles
  int w = tid >> 6, l = tid & 63;
  int wr = w >> 1, wcq = w & 1;
  int lr = l & 15, lk = l >> 4;
  f32x4 acc[2][2] = {};

  for (int kt = 0; kt < 8; kt++) {
    // ---- stage A: 8 coalesced fp32 loads (k-strided), split hi/lo, 2x ds_write_b128
    {
      int kbase = (bt * 256 + kt * 32 + aoct * 8) * 576 + hw0 + ar;
      ushortT hi[8], lo[8];
#pragma unroll
      for (int j = 0; j < 8; j++) {
        float v = bf ? bf2f(xB[kbase + j * 576]) : xF[kbase + j * 576];
        ushortT h = f2bf(v);
        hi[j] = h;
        lo[j] = f2bf(v - bf2f(h));
      }
      int4 ph, pl;
      ph.x = (int)((unsigned)hi[0] | ((unsigned)hi[1] << 16));
      ph.y = (int)((unsigned)hi[2] | ((unsigned)hi[3] << 16));
      ph.z = (int)((unsigned)hi[4] | ((unsigned)hi[5] << 16));
      ph.w = (int)((unsigned)hi[6] | ((unsigned)hi[7] << 16));
      pl.x = (int)((unsigned)lo[0] | ((unsigned)lo[1] << 16));
      pl.y = (int)((unsigned)lo[2] | ((unsigned)lo[3] << 16));
      pl.z = (int)((unsigned)lo[4] | ((unsigned)lo[5] << 16));
      pl.w = (int)((unsigned)lo[6] | ((unsigned)lo[7] << 16));
      *(int4*)&Ah[ar * 40 + aoct * 8] = ph;
      *(int4*)&Al[ar * 40 + aoct * 8] = pl;
    }
    // ---- stage B: 8 fp32 (k-contiguous), split hi/lo, 2x ds_write_b128
    {
      float vb[8];
      if (isW) {
        if (bf) {
          const ushortT* pp = wB + (col0 + bn) * 256 + kt * 32 + bko * 8;
#pragma unroll
          for (int j = 0; j < 8; j++) vb[j] = bf2f(pp[j]);
        } else {
          const float* pp = wF + (col0 + bn) * 256 + kt * 32 + bko * 8;
          float4 f0 = *(const float4*)pp;
          float4 f1 = *(const float4*)(pp + 4);
          vb[0] = f0.x; vb[1] = f0.y; vb[2] = f0.z; vb[3] = f0.w;
          vb[4] = f1.x; vb[5] = f1.y; vb[6] = f1.z; vb[7] = f1.w;
        }
      } else {
        const float* pp = wc + (col0 - 256 + bn) * 256 + kt * 32 + bko * 8;
        float4 f0 = *(const float4*)pp;
        float4 f1 = *(const float4*)(pp + 4);
        vb[0] = f0.x; vb[1] = f0.y; vb[2] = f0.z; vb[3] = f0.w;
        vb[4] = f1.x; vb[5] = f1.y; vb[6] = f1.z; vb[7] = f1.w;
      }
      ushortT hi[8], lo[8];
#pragma unroll
      for (int j = 0; j < 8; j++) {
        ushortT h = f2bf(vb[j]);
        hi[j] = h;
        lo[j] = f2bf(vb[j] - bf2f(h));
      }
      int4 ph, pl;
      ph.x = (int)((unsigned)hi[0] | ((unsigned)hi[1] << 16));
      ph.y = (int)((unsigned)hi[2] | ((unsigned)hi[3] << 16));
      ph.z = (int)((unsigned)hi[4] | ((unsigned)hi[5] << 16));
      ph.w = (int)((unsigned)hi[6] | ((unsigned)hi[7] << 16));
      pl.x = (int)((unsigned)lo[0] | ((unsigned)lo[1] << 16));
      pl.y = (int)((unsigned)lo[2] | ((unsigned)lo[3] << 16));
      pl.z = (int)((unsigned)lo[4] | ((unsigned)lo[5] << 16));
      pl.w = (int)((unsigned)lo[6] | ((unsigned)lo[7] << 16));
      *(int4*)&Bh[bn * 40 + bko * 8] = ph;
      *(int4*)&Bl[bn * 40 + bko * 8] = pl;
    }
    __syncthreads();
    // ---- fragments: A row = l&15, k = (l>>4)*8+j ; B col = l&15, same k
    bf16x8 a0h = *(const bf16x8*)&Ah[(wr * 32 + 0 * 16 + lr) * 40 + lk * 8];
    bf16x8 a1h = *(const bf16x8*)&Ah[(wr * 32 + 1 * 16 + lr) * 40 + lk * 8];
    bf16x8 a0l = *(const bf16x8*)&Al[(wr * 32 + 0 * 16 + lr) * 40 + lk * 8];
    bf16x8 a1l = *(const bf16x8*)&Al[(wr * 32 + 1 * 16 + lr) * 40 + lk * 8];
    bf16x8 b0h = *(const bf16x8*)&Bh[(wcq * 32 + 0 * 16 + lr) * 40 + lk * 8];
    bf16x8 b1h = *(const bf16x8*)&Bh[(wcq * 32 + 1 * 16 + lr) * 40 + lk * 8];
    bf16x8 b0l = *(const bf16x8*)&Bl[(wcq * 32 + 0 * 16 + lr) * 40 + lk * 8];
    bf16x8 b1l = *(const bf16x8*)&Bl[(wcq * 32 + 1 * 16 + lr) * 40 + lk * 8];
    acc[0][0] = __builtin_amdgcn_mfma_f32_16x16x32_bf16(a0h, b0h, acc[0][0], 0, 0, 0);
    acc[0][0] = __builtin_amdgcn_mfma_f32_16x16x32_bf16(a0h, b0l, acc[0][0], 0, 0, 0);
    acc[0][0] = __builtin_amdgcn_mfma_f32_16x16x32_bf16(a0l, b0h, acc[0][0], 0, 0, 0);
    acc[0][1] = __builtin_amdgcn_mfma_f32_16x16x32_bf16(a0h, b1h, acc[0][1], 0, 0, 0);
    acc[0][1] = __builtin_amdgcn_mfma_f32_16x16x32_bf16(a0h, b1l, acc[0][1], 0, 0, 0);
    acc[0][1] = __builtin_amdgcn_mfma_f32_16x16x32_bf16(a0l, b1h, acc[0][1], 0, 0, 0);
    acc[1][0] = __builtin_amdgcn_mfma_f32_16x16x32_bf16(a1h, b0h, acc[1][0], 0, 0, 0);
    acc[1][0] = __builtin_amdgcn_mfma_f32_16x16x32_bf16(a1h, b0l, acc[1][0], 0, 0, 0);
    acc[1][0] = __builtin_amdgcn_mfma_f32_16x16x32_bf16(a1l, b0h, acc[1][0], 0, 0, 0);
    acc[1][1] = __builtin_amdgcn_mfma_f32_16x16x32_bf16(a1h, b1h, acc[1][1], 0, 0, 0);
    acc[1][1] = __builtin_amdgcn_mfma_f32_16x16x32_bf16(a1h, b1l, acc[1][1], 0, 0, 0);
    acc[1][1] = __builtin_amdgcn_mfma_f32_16x16x32_bf16(a1l, b1h, acc[1][1], 0, 0, 0);
    __syncthreads();
  }
  // ---- epilogue: C/D col=lane&15, row=(lane>>4)*4+reg (verified mapping)
#pragma unroll
  for (int m = 0; m < 2; m++) {
#pragma unroll
    for (int n = 0; n < 2; n++) {
#pragma unroll
      for (int i = 0; i < 4; i++) {
        int row = row0 + wr * 32 + m * 16 + lk * 4 + i;
        int col = col0 + wcq * 32 + n * 16 + lr;
        float v = acc[m][n][i] + bias512[col];
        if (isW) xc[row * 256 + col] = v;
        else     qb[row * 256 + (col - 256)] = f2bf(v);
      }
    }
  }
}

// ---------------- offsets: tap-parallel dw-conv + LN + GELU + proj + ref + clip ----------------
// 256 threads: 8 lane-groups x 32ch; taps distributed across groups; weights staged in LDS.
__global__ __launch_bounds__(256) void k_offsets(const ushortT* qb, const void* w_dw, const void* b_dw,
                                                 const void* ln_g, const void* ln_b, const void* w_proj,
                                                 float* pos, const int* flag) {
  __shared__ float wdw[243 * 33];   // [tap][ch], stride 33 (staging + read bank-clean)
  __shared__ float part[8][33];
  int bid = blockIdx.x;             // g*36 + nn
  int g = bid / 36, nn = bid % 36;
  int b = g >> 3, nh = g & 7;
  int tk = nn / 9, hk = (nn / 3) % 3, wk = nn % 3;
  int tid = threadIdx.x;
  int ch = tid & 31, grp = tid >> 5;
  int bf = flag[0];
  // stage weights transposed: src linear [ch][tap] -> LDS [tap][ch]
  for (int i = tid; i < 7776; i += 256) {
    int c = i / 243, tap = i % 243;
    wdw[tap * 33 + c] = ldg_f(w_dw, i, bf);
  }
  __syncthreads();
  float sum = 0.f;
  for (int tap = grp; tap < 243; tap += 8) {
    int dt = tap / 81, rem = tap % 81, dh = rem / 9, dw = rem % 9;
    int t = tk * 2 - 1 + dt, h = hk * 8 - 4 + dh, w = wk * 8 - 4 + dw;
    if (t < 0 || t >= 8 || h < 0 || h >= 24 || w < 0 || w >= 24) continue;
    float qv = bf2f(qb[((b * 8 + t) * 576 + h * 24 + w) * 256 + nh * 32 + ch]);
    sum += qv * wdw[tap * 33 + ch];
  }
  part[grp][ch] = sum;
  __syncthreads();
  if (tid < 32) {
    float v = ldg_f(b_dw, ch, bf);
#pragma unroll
    for (int j = 0; j < 8; j++) v += part[j][ch];
    float s1 = v;
    for (int m = 16; m; m >>= 1) s1 += __shfl_xor(s1, m);
    float mu = s1 * (1.f / 32.f);
    float d = v - mu;
    float s2 = d * d;
    for (int m = 16; m; m >>= 1) s2 += __shfl_xor(s2, m);
    float o = d * rsqrtf(s2 * (1.f / 32.f) + 1e-5f) * ldg_f(ln_g, ch, bf) + ldg_f(ln_b, ch, bf);
    o = 0.5f * o * (1.f + erff(o * 0.70710678118654752f));
    float res[3];
#pragma unroll
    for (int p = 0; p < 3; p++) {
      float t3 = o * ldg_f(w_proj, p * 32 + ch, bf);
      for (int m = 16; m; m >>= 1) t3 += __shfl_xor(t3, m);
      res[p] = t3;
    }
    if (ch == 0) {
      float ref0 = ((tk + 0.5f) / 3.f) * 2.f - 1.f;
      float ref1 = ((hk + 0.5f) / 2.f) * 2.f - 1.f;
      float ref2 = ((wk + 0.5f) / 2.f) * 2.f - 1.f;
      pos[bid * 3 + 0] = fminf(1.f, fmaxf(-1.f, res[0] + ref0));
      pos[bid * 3 + 1] = fminf(1.f, fmaxf(-1.f, res[1] + ref1));
      pos[bid * 3 + 2] = fminf(1.f, fmaxf(-1.f, res[2] + ref2));
    }
  }
}

// ---------------- fused trilinear sample + k/v 1x1 conv (sel per block) ----------------
__global__ __launch_bounds__(256) void k_svkv(const float* xc_rm, const float* pos,
                                              const void* w_k, const void* b_k,
                                              const void* w_v, const void* b_v,
                                              float* k_rm, float* v_rm, const int* flag) {
  int bx = blockIdx.x;            // (b*36+nn)*2 + sel
  int sel = bx & 1, row = bx >> 1;
  int b = row / 36, nn = row % 36;
  int tid = threadIdx.x;
  int bf = flag[0];
  __shared__ float a[256];
  {
    int nh = tid >> 5;
    int g = b * 8 + nh;
    float p0 = pos[(g * 36 + nn) * 3 + 0];
    float p1 = pos[(g * 36 + nn) * 3 + 1];
    float p2 = pos[(g * 36 + nn) * 3 + 2];
    // faithful: gx=pos_t -> W axis, gy=pos_x -> H axis, gz=pos_y -> T axis
    float ix = (p0 + 1.f) * 0.5f * 23.f;
    float iy = (p2 + 1.f) * 0.5f * 23.f;
    float iz = (p1 + 1.f) * 0.5f * 7.f;
    float x0f = floorf(ix), y0f = floorf(iy), z0f = floorf(iz);
    float fx = ix - x0f, fy = iy - y0f, fz = iz - z0f;
    int x0 = min(max((int)x0f, 0), 23), x1 = min(x0 + 1, 23);
    int y0 = min(max((int)y0f, 0), 23), y1 = min(y0 + 1, 23);
    int z0 = min(max((int)z0f, 0), 7),  z1 = min(z0 + 1, 7);
#define AT(z, y, x) xc_rm[(((b * 8 + (z)) * 576 + (y) * 24 + (x)) * 256 + tid)]
    a[tid] =
      AT(z0, y0, x0) * (1.f - fz) * (1.f - fy) * (1.f - fx) + AT(z0, y0, x1) * (1.f - fz) * (1.f - fy) * fx +
      AT(z0, y1, x0) * (1.f - fz) * fy * (1.f - fx)         + AT(z0, y1, x1) * (1.f - fz) * fy * fx +
      AT(z1, y0, x0) * fz * (1.f - fy) * (1.f - fx)         + AT(z1, y0, x1) * fz * (1.f - fy) * fx +
      AT(z1, y1, x0) * fz * fy * (1.f - fx)                 + AT(z1, y1, x1) * fz * fy * fx;
#undef AT
  }
  __syncthreads();
  const void* w = sel ? w_v : w_k;
  const void* bb = sel ? b_v : b_k;
  float s = 0.f;
  if (bf) {
    const ushortT* wp = (const ushortT*)w + tid * 256;
#pragma unroll 4
    for (int c = 0; c < 256; c += 8) {
      ushort4 k0 = *(const ushort4*)(wp + c), k1 = *(const ushort4*)(wp + c + 4);
      s += a[c+0]*bf2f(k0.x) + a[c+1]*bf2f(k0.y) + a[c+2]*bf2f(k0.z) + a[c+3]*bf2f(k0.w)
         + a[c+4]*bf2f(k1.x) + a[c+5]*bf2f(k1.y) + a[c+6]*bf2f(k1.z) + a[c+7]*bf2f(k1.w);
    }
  } else {
    const float* wp = (const float*)w + tid * 256;
#pragma unroll 4
    for (int c = 0; c < 256; c += 4) {
      float4 k4 = *(const float4*)(wp + c);
      s += a[c]*k4.x + a[c+1]*k4.y + a[c+2]*k4.z + a[c+3]*k4.w;
    }
  }
  float* outp = sel ? v_rm : k_rm;
  outp[row * 256 + tid] = s + ldg_f(bb, tid, bf);
}

// ---------------- attention: QK + log-CPB bias + softmax + PV ----------------
__global__ __launch_bounds__(256) void k_attn(const ushortT* qb, const float* k_rm, const float* v_rm,
                                              const float* pos, const void* rpe_w1, const void* rpe_b1,
                                              const void* rpe_w2, void* outp, const int* flag) {
  __shared__ float ks[36][32];
  __shared__ float vs[36][32];
  __shared__ float poss[36][4];
  __shared__ float4 wab[32];
  __shared__ float w2s[32];
  int g = blockIdx.y, b = g >> 3, nh = g & 7;
  int tid = threadIdx.x;
  int bf = flag[0];
  for (int e = tid; e < 36 * 32; e += 256) {
    int nn = e >> 5, ch = e & 31;
    ks[nn][ch] = k_rm[(b * 36 + nn) * 256 + nh * 32 + ch];
    vs[nn][ch] = v_rm[(b * 36 + nn) * 256 + nh * 32 + ch];
  }
  if (tid < 32) {
    wab[tid] = make_float4(ldg_f(rpe_w1, tid * 3 + 0, bf), ldg_f(rpe_w1, tid * 3 + 1, bf),
                           ldg_f(rpe_w1, tid * 3 + 2, bf), ldg_f(rpe_b1, tid, bf));
    w2s[tid] = ldg_f(rpe_w2, tid, bf);
  }
  if (tid < 108) poss[tid / 3][tid % 3] = pos[g * 108 + tid];
  __syncthreads();

  int mm = blockIdx.x * 256 + tid;
  int t = mm / 576, hw = mm % 576, hh = hw / 24, wwi = hw % 24;
  float qreg[32];
  const ushort4* qp = (const ushort4*)&qb[(b * 4608 + mm) * 256 + nh * 32];
#pragma unroll
  for (int i = 0; i < 8; i++) {
    ushort4 u = qp[i];
    qreg[i * 4 + 0] = bf2f(u.x); qreg[i * 4 + 1] = bf2f(u.y);
    qreg[i * 4 + 2] = bf2f(u.z); qreg[i * 4 + 3] = bf2f(u.w);
  }
  float qg0 = t * (2.f / 7.f) - 1.f;
  float qg1 = hh * (2.f / 23.f) - 1.f;
  float qg2 = wwi * (2.f / 23.f) - 1.f;
  const float scale = 0.17677669529663687f;
  float p[36];
  float mx = -1e30f;
#pragma unroll
  for (int nn = 0; nn < 36; nn++) {
    float s = 0.f;
#pragma unroll
    for (int ch = 0; ch < 32; ch++) s += qreg[ch] * ks[nn][ch];
    float d0 = (qg0 - poss[nn][0]) * 4.f;
    float d1 = (qg1 - poss[nn][1]) * 4.f;
    float d2 = (qg2 - poss[nn][2]) * 4.f;
    d0 = copysignf(__log2f(fabsf(d0) + 1.f) * (1.f / 3.f), d0);
    d1 = copysignf(__log2f(fabsf(d1) + 1.f) * (1.f / 3.f), d1);
    d2 = copysignf(__log2f(fabsf(d2) + 1.f) * (1.f / 3.f), d2);
    float bias = 0.f;
#pragma unroll
    for (int h = 0; h < 32; h++) {
      float4 w = wab[h];
      float hb = fmaf(d0, w.x, fmaf(d1, w.y, fmaf(d2, w.z, w.w)));
      bias = fmaf(fmaxf(hb, 0.f), w2s[h], bias);
    }
    float L = fmaf(s, scale, bias);
    p[nn] = L;
    mx = fmaxf(mx, L);
  }
  float se = 0.f;
#pragma unroll
  for (int nn = 0; nn < 36; nn++) {
    float e = __expf(p[nn] - mx);
    p[nn] = e;
    se += e;
  }
  float inv = 1.f / se;
  float acc[32] = {};
#pragma unroll
  for (int nn = 0; nn < 36; nn++) {
    float pr = p[nn] * inv;
#pragma unroll
    for (int ch = 0; ch < 32; ch++) acc[ch] += pr * vs[nn][ch];
  }
  int obase = ((b * 8 + t) * 256 + nh * 32) * 576 + hw;
  if (bf) {
    __hip_bfloat16* o = (__hip_bfloat16*)outp;
#pragma unroll
    for (int ch = 0; ch < 32; ch++) o[obase + ch * 576] = __float2bfloat16(acc[ch]);
  } else {
    float* o = (float*)outp;
#pragma unroll
    for (int ch = 0; ch < 32; ch++) o[obase + ch * 576] = acc[ch];
  }
}

extern "C" void kernel_launch(void* const* d_in, const int* in_sizes, int n_in,
                              void* d_out, int out_size, void* d_ws, size_t ws_size,
                              hipStream_t stream) {
  const void* x        = d_in[0];
  const void* w_in     = d_in[1];
  const void* b_in     = d_in[2];
  const void* w_q      = d_in[3];
  const void* b_q      = d_in[4];
  const void* w_off_dw = d_in[5];
  const void* b_off_dw = d_in[6];
  const void* ln_g     = d_in[7];
  const void* ln_b     = d_in[8];
  const void* w_off_pj = d_in[9];
  const void* w_k      = d_in[10];
  const void* b_k      = d_in[11];
  const void* w_v      = d_in[12];
  const void* b_v      = d_in[13];
  const void* rpe_w1   = d_in[14];
  const void* rpe_b1   = d_in[15];
  const void* rpe_w2   = d_in[16];

  float* ws    = (float*)d_ws;
  float* xc    = ws + WS_XC;
  ushortT* qb  = (ushortT*)(ws + WS_QB);
  float* pos   = ws + WS_POS;
  float* krm   = ws + WS_K;
  float* vrm   = ws + WS_V;
  float* wcf   = ws + WS_WC;
  float* b512  = ws + WS_B512;
  int* flag    = (int*)(ws + WS_FLAG);

  k_detect<<<1, 64, 0, stream>>>(x, flag);
  k_wc<<<256, 256, 0, stream>>>(w_in, b_in, w_q, b_q, wcf, b512, flag);
  k_gemm_mfma<<<1152, 256, 0, stream>>>(x, w_in, wcf, b512, xc, qb, flag);
  k_offsets<<<576, 256, 0, stream>>>(qb, w_off_dw, b_off_dw, ln_g, ln_b, w_off_pj, pos, flag);
  k_svkv<<<144, 256, 0, stream>>>(xc, pos, w_k, b_k, w_v, b_v, krm, vrm, flag);
  k_attn<<<dim3(18, 16), 256, 0, stream>>>(qb, krm, vrm, pos, rpe_w1, rpe_b1, rpe_w2, d_out, flag);
}